// Round 15
// baseline (367.519 us; speedup 1.0000x reference)
//
#include <hip/hip_runtime.h>

#define NN 8
#define TT 8
#define LL 257
#define HH 16
#define CC 64
#define DD 1024
#define QQ 256
#define NQ (NN*QQ)   // 2048

typedef __attribute__((ext_vector_type(4))) float f32x4;
typedef __attribute__((ext_vector_type(4))) unsigned int u32x4;
typedef __attribute__((ext_vector_type(2))) unsigned int u32x2;

static __device__ __forceinline__ float4 ld4(const float* p) { return *(const float4*)p; }

static __device__ __forceinline__ void mfma16(f32x4& d, u32x4 a, u32x4 b) {
  asm("v_mfma_f32_16x16x32_bf16 %0, %1, %2, %0" : "+v"(d) : "v"(a), "v"(b));
}

static __device__ __forceinline__ unsigned int f2bf(float x) {
  unsigned int u = __float_as_uint(x);
  return (u + 0x7fffu + ((u >> 16) & 1u)) >> 16;
}
static __device__ __forceinline__ unsigned int pk2(float lo, float hi) {
  return f2bf(lo) | (f2bf(hi) << 16);
}
static __device__ __forceinline__ unsigned int cvtpk(float lo, float hi) {
  unsigned int r;
  asm("v_cvt_pk_bf16_f32 %0, %1, %2" : "=v"(r) : "v"(lo), "v"(hi));
  return r;
}
static __device__ __forceinline__ float bf2f(unsigned int u) {
  return __uint_as_float(u << 16);
}

typedef __attribute__((address_space(3))) unsigned char lds_t;
typedef const __attribute__((address_space(1))) unsigned char glb_t;
static __device__ __forceinline__ void gld16(const void* g, void* l) {
  __builtin_amdgcn_global_load_lds((glb_t*)g, (lds_t*)l, 16, 0, 0);
}

// ------------------------------------------- fused f32 -> bf16 cvt ----
__global__ __launch_bounds__(256) void cvt_all_kernel(
    const float* __restrict__ inW, const float* __restrict__ outW,
    const float* __restrict__ fcW, const float* __restrict__ pjW,
    const float* __restrict__ syl1, const float* __restrict__ syl2,
    unsigned short* __restrict__ wqb, unsigned short* __restrict__ outwb,
    unsigned short* __restrict__ fcwb, unsigned short* __restrict__ pjwb,
    unsigned short* __restrict__ syl1b, unsigned short* __restrict__ syl2b) {
  const int i = blockIdx.x * 256 + threadIdx.x;
  const float* src; unsigned short* dst; int off;
  if (i < 262144)       { src = inW;  dst = wqb;   off = i; }
  else if (i < 524288)  { src = outW; dst = outwb; off = i - 262144; }
  else if (i < 1572864) { src = fcW;  dst = fcwb;  off = i - 524288; }
  else if (i < 2621440) { src = pjW;  dst = pjwb;  off = i - 1572864; }
  else if (i < 2654208) { src = syl1; dst = syl1b; off = i - 2621440; }
  else                  { src = syl2; dst = syl2b; off = i - 2654208; }
  const float4 v = ld4(src + (size_t)off * 4);
  u32x2 p; p.x = pk2(v.x, v.y); p.y = pk2(v.z, v.w);
  *(u32x2*)(dst + (size_t)off * 4) = p;
}

// ------------------------------------------------- LN (bf16 output) ----
__global__ __launch_bounds__(256) void ln_bf_kernel(const float* __restrict__ in,
    const float* __restrict__ w, const float* __restrict__ b, unsigned short* __restrict__ out) {
  __shared__ float red[16];
  const int tid = threadIdx.x;
  const size_t row = blockIdx.x;
  const float4 v = ((const float4*)(in + row * DD))[tid];
  float s  = v.x + v.y + v.z + v.w;
  float ss = v.x*v.x + v.y*v.y + v.z*v.z + v.w*v.w;
  #pragma unroll
  for (int off = 32; off; off >>= 1) { s += __shfl_xor(s, off); ss += __shfl_xor(ss, off); }
  if ((tid & 63) == 0) { red[tid >> 6] = s; red[8 + (tid >> 6)] = ss; }
  __syncthreads();
  s  = red[0] + red[1] + red[2] + red[3];
  ss = red[8] + red[9] + red[10] + red[11];
  const float mean = s * (1.f / DD);
  const float var  = ss * (1.f / DD) - mean * mean;
  const float inv  = rsqrtf(var + 1e-5f);
  const float4 wv = ((const float4*)w)[tid];
  const float4 bv = ((const float4*)b)[tid];
  float o0 = (v.x - mean) * inv * wv.x + bv.x;
  float o1 = (v.y - mean) * inv * wv.y + bv.y;
  float o2 = (v.z - mean) * inv * wv.z + bv.z;
  float o3 = (v.w - mean) * inv * wv.w + bv.w;
  u32x2 p; p.x = pk2(o0, o1); p.y = pk2(o2, o3);
  *(u32x2*)(out + row * DD + tid * 4) = p;
}

// ----------------------------------------------------- te pipeline ----
__global__ __launch_bounds__(256) void te_mid_kernel(
    const unsigned short* __restrict__ telnb, const float* __restrict__ l1,
    float* __restrict__ midf) {
  const int j = blockIdx.x * 4 + (threadIdx.x >> 6);
  const int l = threadIdx.x & 63;
  const float* lr = l1 + (size_t)j * DD + l * 16;
  float wv[16];
  #pragma unroll
  for (int q = 0; q < 4; ++q) {
    const float4 f = ld4(lr + q * 4);
    wv[q*4] = f.x; wv[q*4+1] = f.y; wv[q*4+2] = f.z; wv[q*4+3] = f.w;
  }
  float acc[8];
  #pragma unroll
  for (int t = 0; t < 8; ++t) {
    const unsigned short* hp = telnb + (size_t)t * DD + l * 16;
    const u32x4 h0 = *(const u32x4*)hp;
    const u32x4 h1 = *(const u32x4*)(hp + 8);
    float a = 0.f;
    #pragma unroll
    for (int e = 0; e < 4; ++e) {
      a += bf2f(h0[e] & 0xffffu) * wv[e*2]   + bf2f(h0[e] >> 16) * wv[e*2+1];
      a += bf2f(h1[e] & 0xffffu) * wv[8+e*2] + bf2f(h1[e] >> 16) * wv[8+e*2+1];
    }
    acc[t] = a;
  }
  #pragma unroll
  for (int off = 1; off < 64; off <<= 1)
    #pragma unroll
    for (int t = 0; t < 8; ++t) acc[t] += __shfl_xor(acc[t], off);
  if (l == 0) {
    #pragma unroll
    for (int t = 0; t < 8; ++t) midf[t * 128 + j] = acc[t];
  }
}

__global__ __launch_bounds__(256) void te_fin_kernel(
    const float* __restrict__ midf, const float* __restrict__ l2,
    const float* __restrict__ te, float* __restrict__ tef) {
  __shared__ float mid_s[8 * 128];
  const int tid = threadIdx.x;
  ((f32x4*)mid_s)[tid] = ((const f32x4*)midf)[tid];
  __syncthreads();
  const int d = blockIdx.x * 32 + (tid >> 3);
  const int jseg = (tid & 7) * 16;
  const float* l2r = l2 + (size_t)d * 128 + jseg;
  float wv[16];
  #pragma unroll
  for (int q = 0; q < 4; ++q) {
    const float4 f = ld4(l2r + q * 4);
    wv[q*4] = f.x; wv[q*4+1] = f.y; wv[q*4+2] = f.z; wv[q*4+3] = f.w;
  }
  float acc[8];
  #pragma unroll
  for (int t = 0; t < 8; ++t) {
    float a = 0.f;
    #pragma unroll
    for (int i = 0; i < 16; ++i) a += mid_s[t * 128 + jseg + i] * wv[i];
    acc[t] = a;
  }
  #pragma unroll
  for (int off = 1; off < 8; off <<= 1)
    #pragma unroll
    for (int t = 0; t < 8; ++t) acc[t] += __shfl_xor(acc[t], off);
  if ((tid & 7) == 0) {
    #pragma unroll
    for (int t = 0; t < 8; ++t)
      tef[(size_t)t * DD + d] = te[(size_t)t * DD + d] + acc[t];
  }
}

__global__ __launch_bounds__(256) void te_kv2_kernel(
    const float* __restrict__ tef, const float* __restrict__ W, const float* __restrict__ bias,
    float* __restrict__ tek, float* __restrict__ tev) {
  __shared__ float tes[8 * 1024];
  const int tid = threadIdx.x;
  #pragma unroll
  for (int i = 0; i < 8; ++i)
    ((f32x4*)tes)[tid + i * 256] = ((const f32x4*)tef)[tid + i * 256];
  __syncthreads();
  const int o = blockIdx.x * 32 + (tid >> 3);
  const int ks0 = (tid & 7) * 128;
  const float* wr = W + (size_t)(1024 + o) * DD + ks0;
  float acc[8] = {};
  for (int kk = 0; kk < 128; kk += 4) {
    const float4 w4 = ld4(wr + kk);
    #pragma unroll
    for (int t = 0; t < 8; ++t) {
      const float4 h4 = ld4(tes + t * 1024 + ks0 + kk);
      acc[t] += w4.x*h4.x + w4.y*h4.y + w4.z*h4.z + w4.w*h4.w;
    }
  }
  #pragma unroll
  for (int off = 1; off < 8; off <<= 1)
    #pragma unroll
    for (int t = 0; t < 8; ++t) acc[t] += __shfl_xor(acc[t], off);
  if ((tid & 7) == 0) {
    const float bv = bias[1024 + o];
    float* dst = (o < 1024) ? tek : tev;
    const int oc = o & 1023;
    #pragma unroll
    for (int t = 0; t < 8; ++t) dst[(size_t)t * DD + oc] = acc[t] + bv;
  }
}

// --------------------------------- bf16 MFMA GEMM (proven 2-phase) ----
// Instantiated ONLY at proven shapes: <EPI,64,128> and <2,128,128>.
// QUARANTINE (bisect-convicted, mechanism unknown): BN=64 tiles (R9/R10),
// 2-deep counted-vmcnt pipeline (R6/R7), attn register prefetch (R13).
template<int EPI, int BM, int BN>
__global__ __launch_bounds__(256, 2) void gemm_bf(
    const unsigned short* __restrict__ A, const unsigned short* __restrict__ W,
    const float* __restrict__ bias, const float* __restrict__ res,
    void* __restrict__ Cv, int M, int N, int K, int ny) {
  constexpr int FR = BM / 32;
  constexpr int NB = BN / 32;
  __shared__ unsigned short As[2][BM * 64];
  __shared__ unsigned short Bs[2][BN * 64];
  const int tid = threadIdx.x, w = tid >> 6, l = tid & 63;
  const int lc = l & 15, lg = l >> 4;
  const int nb = gridDim.x;
  const int cid = (blockIdx.x & 7) * (nb >> 3) + (blockIdx.x >> 3);  // XCD chunk
  const int bxt = cid / ny, byt = cid - bxt * ny;
  const int m0 = byt * BM, n0 = bxt * BN;
  const int wm = (w >> 1) * (BM / 2), wn = (w & 1) * (BN / 2);
  const int rrow = tid >> 3;             // 0..31
  const int sblk = (tid & 7) ^ (rrow & 7);   // pre-swizzled source block

  f32x4 acc[FR][NB] = {};

  auto stagef = [&](int kt, int b) {
    const int k0 = kt * 64 + sblk * 8;
    #pragma unroll
    for (int r = 0; r < FR; ++r)
      gld16(A + (size_t)(m0 + r * 32 + rrow) * K + k0, &As[b][r * 2048 + w * 512]);
    #pragma unroll
    for (int r = 0; r < NB; ++r)
      gld16(W + (size_t)(n0 + r * 32 + rrow) * K + k0, &Bs[b][r * 2048 + w * 512]);
  };
  auto computef = [&](int b) {
    const int kx = lc & 7;
    #pragma unroll
    for (int ks = 0; ks < 2; ++ks) {
      u32x4 af[FR], bfr[NB];
      #pragma unroll
      for (int i = 0; i < FR; ++i)
        af[i] = *(const u32x4*)&As[b][(wm + i * 16 + lc) * 64 + ((ks * 4 + lg) ^ kx) * 8];
      #pragma unroll
      for (int j = 0; j < NB; ++j)
        bfr[j] = *(const u32x4*)&Bs[b][(wn + j * 16 + lc) * 64 + ((ks * 4 + lg) ^ kx) * 8];
      #pragma unroll
      for (int i = 0; i < FR; ++i)
        #pragma unroll
        for (int j = 0; j < NB; ++j)
          mfma16(acc[i][j], af[i], bfr[j]);
    }
  };

  const int NT = K >> 6;
  stagef(0, 0);
  asm volatile("s_waitcnt vmcnt(0)" ::: "memory");
  __builtin_amdgcn_s_barrier();
  int cur = 0;
  for (int kt = 0; kt < NT - 1; ++kt) {
    stagef(kt + 1, cur ^ 1);
    computef(cur);
    asm volatile("s_waitcnt vmcnt(0)" ::: "memory");
    __builtin_amdgcn_s_barrier();
    cur ^= 1;
  }
  computef(cur);

  float bias4[NB];
  if (EPI == 1 || EPI == 2 || EPI == 3) {
    #pragma unroll
    for (int j = 0; j < NB; ++j) bias4[j] = bias[n0 + wn + j * 16 + lc];
  }
  #pragma unroll
  for (int i = 0; i < FR; ++i) {
    #pragma unroll
    for (int j = 0; j < NB; ++j) {
      const int col = n0 + wn + j * 16 + lc;
      #pragma unroll
      for (int r = 0; r < 4; ++r) {
        const int row = m0 + wm + i * 16 + lg * 4 + r;
        float x = acc[i][j][r];
        if (EPI == 0) {
          ((unsigned short*)Cv)[(size_t)row * N + col] = (unsigned short)f2bf(x);
        } else if (EPI == 1) {
          x = (x + bias4[j]) * 0.125f;
          ((unsigned short*)Cv)[(size_t)row * N + col] = (unsigned short)f2bf(x);
        } else if (EPI == 2) {
          x += bias4[j];
          x = x / (1.f + __expf(-1.702f * x));
          ((unsigned short*)Cv)[(size_t)row * N + col] = (unsigned short)f2bf(x);
        } else if (EPI == 3) {
          x += bias4[j] + res[(size_t)row * N + col];
          ((float*)Cv)[(size_t)row * N + col] = x;
        } else {
          x += res[(size_t)row * N + col];
          ((float*)Cv)[(size_t)row * N + col] = x;
        }
      }
    }
  }
}

// -------------------------------------------------- MFMA attention ----
// R15: coarsened proven pattern — 2 iterations of {sync, stage 128 keys,
// sync, compute sub0, compute sub1}. Same sync skeleton as R12/R14 (no
// register data across barriers, single-buffered LDS, Pl wave-private);
// half the barriers, 2x staging MLP. LDS = 18432+17408+34816 = 70656 B.
__global__ __launch_bounds__(256, 2) void attn_mfma(
    const float* __restrict__ ak, const float* __restrict__ av,
    const unsigned short* __restrict__ qbf,
    const float* __restrict__ tek, const float* __restrict__ tev,
    const float* __restrict__ mask, unsigned short* __restrict__ smix) {
  const int h = blockIdx.x, t = blockIdx.y, n = blockIdx.z;
  const int tid = threadIdx.x, w = tid >> 6, l = tid & 63;
  const int lc = l & 15, lg = l >> 4;
  constexpr int HC = HH * CC;
  __shared__ unsigned short Ks[128][72];
  __shared__ unsigned short Vt[64][136];
  __shared__ unsigned short Pl[4][64][68];

  u32x4 qf[4][2];
  {
    const unsigned short* qb = qbf + ((size_t)(n * QQ + w * 64 + lc)) * DD + h * CC + lg * 8;
    #pragma unroll
    for (int fnq = 0; fnq < 4; ++fnq)
      #pragma unroll
      for (int ks = 0; ks < 2; ++ks)
        qf[fnq][ks] = *(const u32x4*)(qb + (size_t)fnq * 16 * DD + ks * 32);
  }
  // qte[fnq] = (q*scale) . te_k
  float qte4[4];
  {
    float tkc[16];
    const float* tp = tek + (size_t)t * DD + h * CC + lg * 8;
    #pragma unroll
    for (int ks = 0; ks < 2; ++ks) {
      const float4 a = ld4(tp + ks * 32);
      const float4 b = ld4(tp + ks * 32 + 4);
      tkc[ks*8]   = a.x; tkc[ks*8+1] = a.y; tkc[ks*8+2] = a.z; tkc[ks*8+3] = a.w;
      tkc[ks*8+4] = b.x; tkc[ks*8+5] = b.y; tkc[ks*8+6] = b.z; tkc[ks*8+7] = b.w;
    }
    #pragma unroll
    for (int fnq = 0; fnq < 4; ++fnq) {
      float p = 0.f;
      #pragma unroll
      for (int ks = 0; ks < 2; ++ks)
        #pragma unroll
        for (int e = 0; e < 4; ++e) {
          const unsigned int u = qf[fnq][ks][e];
          p += bf2f(u & 0xffffu) * tkc[ks*8 + e*2];
          p += bf2f(u >> 16)     * tkc[ks*8 + e*2 + 1];
        }
      p += __shfl_xor(p, 16);
      p += __shfl_xor(p, 32);
      qte4[fnq] = p;
    }
  }

  f32x4 oacc[4][4] = {};
  float mrun[4], lrun[4];
  #pragma unroll
  for (int i = 0; i < 4; ++i) { mrun[i] = -1e30f; lrun[i] = 0.f; }

  const size_t krow0 = (((size_t)(n * TT + t) * LL + 1) * HH + h) * CC;
  const float* mbase = mask + (size_t)(w * 64) * QQ;

  for (int chunk = 0; chunk < 2; ++chunk) {
    const int c0 = chunk * 128;
    __syncthreads();
    {   // stage K rows [0..128) of this chunk: thread -> row tid>>1, 32 cols
      const int kr = tid >> 1, cs = (tid & 1) * 32;
      const float* kp = ak + krow0 + (size_t)(c0 + kr) * HC + cs;
      #pragma unroll
      for (int g = 0; g < 2; ++g) {
        const float4 a = ld4(kp + g * 16),     b = ld4(kp + g * 16 + 4);
        const float4 c = ld4(kp + g * 16 + 8), d = ld4(kp + g * 16 + 12);
        u32x4 pa; pa.x = cvtpk(a.x, a.y); pa.y = cvtpk(a.z, a.w);
        pa.z = cvtpk(b.x, b.y); pa.w = cvtpk(b.z, b.w);
        u32x4 pb; pb.x = cvtpk(c.x, c.y); pb.y = cvtpk(c.z, c.w);
        pb.z = cvtpk(d.x, d.y); pb.w = cvtpk(d.z, d.w);
        *(u32x4*)&Ks[kr][cs + g * 16]     = pa;
        *(u32x4*)&Ks[kr][cs + g * 16 + 8] = pb;
      }
    }
    {   // stage V transposed [c][key] for 128 keys (64 pairs)
      const int kp2 = tid & 63, ch = tid >> 6;   // pair 0..63, c-quarter 0..3
      const float* vr0 = av + krow0 + (size_t)(c0 + 2 * kp2) * HC + ch * 16;
      const float* vr1 = vr0 + HC;
      float va[16], vb[16];
      #pragma unroll
      for (int g = 0; g < 4; ++g) {
        const float4 a = ld4(vr0 + g * 4);
        const float4 b = ld4(vr1 + g * 4);
        va[g*4] = a.x; va[g*4+1] = a.y; va[g*4+2] = a.z; va[g*4+3] = a.w;
        vb[g*4] = b.x; vb[g*4+1] = b.y; vb[g*4+2] = b.z; vb[g*4+3] = b.w;
      }
      #pragma unroll
      for (int i = 0; i < 16; ++i)
        *(unsigned int*)&Vt[ch * 16 + i][2 * kp2] = cvtpk(va[i], vb[i]);
    }
    __syncthreads();

    #pragma unroll
    for (int sub = 0; sub < 2; ++sub) {
      const int r0 = sub * 64;          // row offset in Ks / col offset in Vt
      const int c0s = c0 + r0;          // absolute key base

      f32x4 sf[4][4] = {};
      __builtin_amdgcn_s_setprio(1);
      #pragma unroll
      for (int ks = 0; ks < 2; ++ks) {
        u32x4 kf[4];
        #pragma unroll
        for (int fmk = 0; fmk < 4; ++fmk)
          kf[fmk] = *(const u32x4*)&Ks[r0 + fmk * 16 + lc][ks * 32 + lg * 8];
        #pragma unroll
        for (int fmk = 0; fmk < 4; ++fmk)
          #pragma unroll
          for (int fnq = 0; fnq < 4; ++fnq)
            mfma16(sf[fmk][fnq], kf[fmk], qf[fnq][ks]);
      }
      __builtin_amdgcn_s_setprio(0);

      #pragma unroll
      for (int fnq = 0; fnq < 4; ++fnq) {
        const float* mrow = mbase + (size_t)(fnq * 16 + lc) * QQ + c0s + lg * 4;
        const float qv = qte4[fnq];
        #pragma unroll
        for (int fmk = 0; fmk < 4; ++fmk) {
          const f32x4 mk = *(const f32x4*)(mrow + fmk * 16);
          sf[fmk][fnq] += mk + qv;
        }
        float mx = -1e30f;
        #pragma unroll
        for (int fmk = 0; fmk < 4; ++fmk) {
          mx = fmaxf(mx, fmaxf(fmaxf(sf[fmk][fnq][0], sf[fmk][fnq][1]),
                               fmaxf(sf[fmk][fnq][2], sf[fmk][fnq][3])));
        }
        mx = fmaxf(mx, __shfl_xor(mx, 16));
        mx = fmaxf(mx, __shfl_xor(mx, 32));
        const float mnew = fmaxf(mrun[fnq], mx);
        const float corr = __expf(mrun[fnq] - mnew);
        mrun[fnq] = mnew;
        float ls = 0.f;
        #pragma unroll
        for (int fmk = 0; fmk < 4; ++fmk) {
          const float p0 = __expf(sf[fmk][fnq][0] - mnew);
          const float p1 = __expf(sf[fmk][fnq][1] - mnew);
          const float p2 = __expf(sf[fmk][fnq][2] - mnew);
          const float p3 = __expf(sf[fmk][fnq][3] - mnew);
          ls += (p0 + p1) + (p2 + p3);
          u32x2 pw; pw.x = cvtpk(p0, p1); pw.y = cvtpk(p2, p3);
          *(u32x2*)&Pl[w][fnq * 16 + lc][fmk * 16 + lg * 4] = pw;
        }
        ls += __shfl_xor(ls, 16);
        ls += __shfl_xor(ls, 32);
        lrun[fnq] = lrun[fnq] * corr + ls;
        #pragma unroll
        for (int fmc = 0; fmc < 4; ++fmc) oacc[fmc][fnq] *= corr;
      }

      __builtin_amdgcn_s_setprio(1);
      #pragma unroll
      for (int ks = 0; ks < 2; ++ks) {
        u32x4 vf[4], pf[4];
        #pragma unroll
        for (int fmc = 0; fmc < 4; ++fmc)
          vf[fmc] = *(const u32x4*)&Vt[fmc * 16 + lc][r0 + ks * 32 + lg * 8];
        #pragma unroll
        for (int fnq = 0; fnq < 4; ++fnq) {
          const u32x2 pa = *(const u32x2*)&Pl[w][fnq * 16 + lc][ks * 32 + lg * 8];
          const u32x2 pb = *(const u32x2*)&Pl[w][fnq * 16 + lc][ks * 32 + lg * 8 + 4];
          pf[fnq].x = pa.x; pf[fnq].y = pa.y; pf[fnq].z = pb.x; pf[fnq].w = pb.y;
        }
        #pragma unroll
        for (int fmc = 0; fmc < 4; ++fmc)
          #pragma unroll
          for (int fnq = 0; fnq < 4; ++fnq)
            mfma16(oacc[fmc][fnq], vf[fmc], pf[fnq]);
      }
      __builtin_amdgcn_s_setprio(0);
    }
  }

  // epilogue: O/l + te_v  -> smix bf16
  f32x4 tev4[4];
  {
    const float* tvp = tev + (size_t)t * DD + h * CC + lg * 4;
    #pragma unroll
    for (int fmc = 0; fmc < 4; ++fmc) tev4[fmc] = *(const f32x4*)(tvp + fmc * 16);
  }
  #pragma unroll
  for (int fnq = 0; fnq < 4; ++fnq) {
    const float inv = 1.f / lrun[fnq];
    const int qg = w * 64 + fnq * 16 + lc;
    unsigned short* op = smix + ((((size_t)(n * TT + t) * QQ + qg) * HH + h) * CC + lg * 4);
    #pragma unroll
    for (int fmc = 0; fmc < 4; ++fmc) {
      const f32x4 o = oacc[fmc][fnq] * inv + tev4[fmc];
      u32x2 p; p.x = cvtpk(o[0], o[1]); p.y = cvtpk(o[2], o[3]);
      *(u32x2*)(op + fmc * 16) = p;
    }
  }
}

// -------------------------------------------- conv3+mean_t combine ----
__global__ __launch_bounds__(256) void combine_kernel(
    const unsigned short* __restrict__ smix, const float* __restrict__ cw,
    const float* __restrict__ cb, unsigned short* __restrict__ smm) {
  const int nq = blockIdx.x;
  const int d = threadIdx.x * 4;
  const int n = nq >> 8, q = nq & 255;
  const unsigned short* base = smix + ((size_t)n * TT * QQ + q) * DD + d;
  float S[4] = {0.f, 0.f, 0.f, 0.f};
  float X0[4], X7[4];
  #pragma unroll
  for (int t = 0; t < TT; ++t) {
    const u32x2 pv = *(const u32x2*)(base + (size_t)t * QQ * DD);
    const float v[4] = {bf2f(pv.x & 0xffffu), bf2f(pv.x >> 16),
                        bf2f(pv.y & 0xffffu), bf2f(pv.y >> 16)};
    if (t == 0) { X0[0]=v[0]; X0[1]=v[1]; X0[2]=v[2]; X0[3]=v[3]; }
    if (t == 7) { X7[0]=v[0]; X7[1]=v[1]; X7[2]=v[2]; X7[3]=v[3]; }
    #pragma unroll
    for (int i = 0; i < 4; ++i) S[i] += v[i];
  }
  float o[4];
  #pragma unroll
  for (int i = 0; i < 4; ++i) {
    const int chn = d + i;
    const float w0 = cw[chn*3+0], w1 = cw[chn*3+1], w2 = cw[chn*3+2];
    o[i] = ((1.f + w0 + w1 + w2) * S[i] - w0 * X7[i] - w2 * X0[i]) * 0.125f + cb[chn];
  }
  u32x2 p; p.x = pk2(o[0], o[1]); p.y = pk2(o[2], o[3]);
  *(u32x2*)(smm + (size_t)nq * DD + d) = p;
}

// ------------------------------------------------------------ launch ----
extern "C" void kernel_launch(void* const* d_in, const int* in_sizes, int n_in,
                              void* d_out, int out_size, void* d_ws, size_t ws_size,
                              hipStream_t stream) {
  const float* attrs_k = (const float*)d_in[0];
  const float* attrs_v = (const float*)d_in[1];
  const float* s       = (const float*)d_in[2];
  const float* te      = (const float*)d_in[3];
  const float* pmask   = (const float*)d_in[4];
  const float* ln1_w   = (const float*)d_in[5];
  const float* ln1_b   = (const float*)d_in[6];
  const float* inW     = (const float*)d_in[7];
  const float* inB     = (const float*)d_in[8];
  const float* outW    = (const float*)d_in[9];
  const float* outB    = (const float*)d_in[10];
  const float* ln2_w   = (const float*)d_in[11];
  const float* ln2_b   = (const float*)d_in[12];
  const float* fcW     = (const float*)d_in[13];
  const float* fcB     = (const float*)d_in[14];
  const float* pjW     = (const float*)d_in[15];
  const float* pjB     = (const float*)d_in[16];
  const float* sylnW   = (const float*)d_in[17];
  const float* sylnB   = (const float*)d_in[18];
  const float* syl1    = (const float*)d_in[19];
  const float* syl2    = (const float*)d_in[20];
  const float* telnW   = (const float*)d_in[21];
  const float* telnB   = (const float*)d_in[22];
  const float* tel1    = (const float*)d_in[23];
  const float* tel2    = (const float*)d_in[24];
  const float* tconvW  = (const float*)d_in[25];
  const float* tconvB  = (const float*)d_in[26];

  float* ws = (float*)d_ws;
  float*          f_te   = ws;                                  // 8192 (= _te)
  float*          f_tek  = ws + 8192;                           // 8192
  float*          f_tev  = ws + 16384;                          // 8192
  unsigned short* telnb  = (unsigned short*)(ws + 24576);       // 4096 f
  float*          midf   = ws + 28672;                          // 1024 f
  unsigned short* syl1b  = (unsigned short*)(ws + 32768);       // 65536 f
  unsigned short* syl2b  = (unsigned short*)(ws + 98304);       // 65536 f
  unsigned short* midb   = (unsigned short*)(ws + 163840);      // 131072 f
  unsigned short* bufAb  = (unsigned short*)(ws + 327680);      // 524288 f (LN outs)
  unsigned short* qbf    = (unsigned short*)(ws + 851968);      // 524288 f
  unsigned short* smmb   = (unsigned short*)(ws + 1376256);     // 524288 f
  unsigned short* wqb    = (unsigned short*)(ws + 1900544);     // 524288 f
  unsigned short* outwb  = (unsigned short*)(ws + 2424832);     // 524288 f
  unsigned short* fcwb   = (unsigned short*)(ws + 2949120);     // 2097152 f
  unsigned short* pjwb   = (unsigned short*)(ws + 5046272);     // 2097152 f
  float*          bufB   = ws + 7143424;                        // 2097152 f (_s)
  unsigned short* smixb  = (unsigned short*)(ws + 9240576);     // 8388608 f region
  float*          s1     = ws + 9240576;                        // overlay (smix dead)
  unsigned short* hmidb  = (unsigned short*)(ws + 9240576 + 2097152); // 4194304 f
  float*          outp   = (float*)d_out;

  // 0. fused weight conversions f32 -> bf16
  cvt_all_kernel<<<10496, 256, 0, stream>>>(inW, outW, fcW, pjW, syl1, syl2,
                                            wqb, outwb, fcwb, pjwb, syl1b, syl2b);

  // 1. te adaptor pipeline + te k/v
  ln_bf_kernel<<<TT, 256, 0, stream>>>(te, telnW, telnB, telnb);
  te_mid_kernel<<<32, 256, 0, stream>>>(telnb, tel1, midf);
  te_fin_kernel<<<32, 256, 0, stream>>>(midf, tel2, te, f_te);
  te_kv2_kernel<<<64, 256, 0, stream>>>(f_te, inW, inB, f_tek, f_tev);

  // 2. syno adaptor: h = LN(s) [bf16]
  ln_bf_kernel<<<NQ, 256, 0, stream>>>(s, sylnW, sylnB, bufAb);
  // 3. mid = h @ l1^T  [bf16]
  gemm_bf<0, 64, 128><<<32, 256, 0, stream>>>(bufAb, syl1b, nullptr, nullptr, midb, NQ, 128, DD, 32);
  // 4. _s = s + mid @ l2^T  [f32]
  gemm_bf<4, 64, 128><<<256, 256, 0, stream>>>(midb, syl2b, nullptr, s, bufB, NQ, DD, 128, 32);
  // 5. x = LN1(_s) [bf16]
  ln_bf_kernel<<<NQ, 256, 0, stream>>>(bufB, ln1_w, ln1_b, bufAb);
  // 6. s_q = (x @ Wq^T + bq) * 0.125 [bf16]
  gemm_bf<1, 64, 128><<<256, 256, 0, stream>>>(bufAb, wqb, inB, nullptr, qbf, NQ, DD, DD, 32);
  // 7. attention -> smix bf16 (includes te_v)
  attn_mfma<<<dim3(HH, TT, NN), 256, 0, stream>>>(attrs_k, attrs_v, qbf, f_tek, f_tev, pmask, smixb);
  // 8. conv+mean combine -> smm bf16
  combine_kernel<<<NQ, 256, 0, stream>>>(smixb, tconvW, tconvB, smmb);
  // 9. s1 = s + smm @ outW^T + outB [f32]
  gemm_bf<3, 64, 128><<<256, 256, 0, stream>>>(smmb, outwb, outB, s, s1, NQ, DD, DD, 32);
  // 10. x2 = LN2(s1) [bf16]
  ln_bf_kernel<<<NQ, 256, 0, stream>>>(s1, ln2_w, ln2_b, bufAb);
  // 11. hmid = qgelu(x2 @ fcW^T + fcB) [bf16] (128x128 tile)
  gemm_bf<2, 128, 128><<<512, 256, 0, stream>>>(bufAb, fcwb, fcB, nullptr, hmidb, NQ, 4 * DD, DD, 16);
  // 12. out = s1 + hmid @ pjW^T + pjB [f32]
  gemm_bf<3, 64, 128><<<256, 256, 0, stream>>>(hmidb, pjwb, pjB, s1, outp, NQ, DD, 4 * DD, 32);
}

// Round 16
// 259.664 us; speedup vs baseline: 1.4154x; 1.4154x over previous
//
#include <hip/hip_runtime.h>

#define NN 8
#define TT 8
#define LL 257
#define HH 16
#define CC 64
#define DD 1024
#define QQ 256
#define NQ (NN*QQ)   // 2048

typedef __attribute__((ext_vector_type(4))) float f32x4;
typedef __attribute__((ext_vector_type(4))) unsigned int u32x4;
typedef __attribute__((ext_vector_type(2))) unsigned int u32x2;

static __device__ __forceinline__ float4 ld4(const float* p) { return *(const float4*)p; }

static __device__ __forceinline__ void mfma16(f32x4& d, u32x4 a, u32x4 b) {
  asm("v_mfma_f32_16x16x32_bf16 %0, %1, %2, %0" : "+v"(d) : "v"(a), "v"(b));
}

static __device__ __forceinline__ unsigned int f2bf(float x) {
  unsigned int u = __float_as_uint(x);
  return (u + 0x7fffu + ((u >> 16) & 1u)) >> 16;
}
static __device__ __forceinline__ unsigned int pk2(float lo, float hi) {
  return f2bf(lo) | (f2bf(hi) << 16);
}
static __device__ __forceinline__ unsigned int cvtpk(float lo, float hi) {
  unsigned int r;
  asm("v_cvt_pk_bf16_f32 %0, %1, %2" : "=v"(r) : "v"(lo), "v"(hi));
  return r;
}
static __device__ __forceinline__ float bf2f(unsigned int u) {
  return __uint_as_float(u << 16);
}

typedef __attribute__((address_space(3))) unsigned char lds_t;
typedef const __attribute__((address_space(1))) unsigned char glb_t;
static __device__ __forceinline__ void gld16(const void* g, void* l) {
  __builtin_amdgcn_global_load_lds((glb_t*)g, (lds_t*)l, 16, 0, 0);
}

// ------------------------------------------- fused f32 -> bf16 cvt ----
__global__ __launch_bounds__(256) void cvt_all_kernel(
    const float* __restrict__ inW, const float* __restrict__ outW,
    const float* __restrict__ fcW, const float* __restrict__ pjW,
    const float* __restrict__ syl1, const float* __restrict__ syl2,
    unsigned short* __restrict__ wqb, unsigned short* __restrict__ outwb,
    unsigned short* __restrict__ fcwb, unsigned short* __restrict__ pjwb,
    unsigned short* __restrict__ syl1b, unsigned short* __restrict__ syl2b) {
  const int i = blockIdx.x * 256 + threadIdx.x;
  const float* src; unsigned short* dst; int off;
  if (i < 262144)       { src = inW;  dst = wqb;   off = i; }
  else if (i < 524288)  { src = outW; dst = outwb; off = i - 262144; }
  else if (i < 1572864) { src = fcW;  dst = fcwb;  off = i - 524288; }
  else if (i < 2621440) { src = pjW;  dst = pjwb;  off = i - 1572864; }
  else if (i < 2654208) { src = syl1; dst = syl1b; off = i - 2621440; }
  else                  { src = syl2; dst = syl2b; off = i - 2654208; }
  const float4 v = ld4(src + (size_t)off * 4);
  u32x2 p; p.x = pk2(v.x, v.y); p.y = pk2(v.z, v.w);
  *(u32x2*)(dst + (size_t)off * 4) = p;
}

// ------------------------------------------------- LN (bf16 output) ----
__global__ __launch_bounds__(256) void ln_bf_kernel(const float* __restrict__ in,
    const float* __restrict__ w, const float* __restrict__ b, unsigned short* __restrict__ out) {
  __shared__ float red[16];
  const int tid = threadIdx.x;
  const size_t row = blockIdx.x;
  const float4 v = ((const float4*)(in + row * DD))[tid];
  float s  = v.x + v.y + v.z + v.w;
  float ss = v.x*v.x + v.y*v.y + v.z*v.z + v.w*v.w;
  #pragma unroll
  for (int off = 32; off; off >>= 1) { s += __shfl_xor(s, off); ss += __shfl_xor(ss, off); }
  if ((tid & 63) == 0) { red[tid >> 6] = s; red[8 + (tid >> 6)] = ss; }
  __syncthreads();
  s  = red[0] + red[1] + red[2] + red[3];
  ss = red[8] + red[9] + red[10] + red[11];
  const float mean = s * (1.f / DD);
  const float var  = ss * (1.f / DD) - mean * mean;
  const float inv  = rsqrtf(var + 1e-5f);
  const float4 wv = ((const float4*)w)[tid];
  const float4 bv = ((const float4*)b)[tid];
  float o0 = (v.x - mean) * inv * wv.x + bv.x;
  float o1 = (v.y - mean) * inv * wv.y + bv.y;
  float o2 = (v.z - mean) * inv * wv.z + bv.z;
  float o3 = (v.w - mean) * inv * wv.w + bv.w;
  u32x2 p; p.x = pk2(o0, o1); p.y = pk2(o2, o3);
  *(u32x2*)(out + row * DD + tid * 4) = p;
}

// ----------------------------------------------------- te pipeline ----
__global__ __launch_bounds__(256) void te_mid_kernel(
    const unsigned short* __restrict__ telnb, const float* __restrict__ l1,
    float* __restrict__ midf) {
  const int j = blockIdx.x * 4 + (threadIdx.x >> 6);
  const int l = threadIdx.x & 63;
  const float* lr = l1 + (size_t)j * DD + l * 16;
  float wv[16];
  #pragma unroll
  for (int q = 0; q < 4; ++q) {
    const float4 f = ld4(lr + q * 4);
    wv[q*4] = f.x; wv[q*4+1] = f.y; wv[q*4+2] = f.z; wv[q*4+3] = f.w;
  }
  float acc[8];
  #pragma unroll
  for (int t = 0; t < 8; ++t) {
    const unsigned short* hp = telnb + (size_t)t * DD + l * 16;
    const u32x4 h0 = *(const u32x4*)hp;
    const u32x4 h1 = *(const u32x4*)(hp + 8);
    float a = 0.f;
    #pragma unroll
    for (int e = 0; e < 4; ++e) {
      a += bf2f(h0[e] & 0xffffu) * wv[e*2]   + bf2f(h0[e] >> 16) * wv[e*2+1];
      a += bf2f(h1[e] & 0xffffu) * wv[8+e*2] + bf2f(h1[e] >> 16) * wv[8+e*2+1];
    }
    acc[t] = a;
  }
  #pragma unroll
  for (int off = 1; off < 64; off <<= 1)
    #pragma unroll
    for (int t = 0; t < 8; ++t) acc[t] += __shfl_xor(acc[t], off);
  if (l == 0) {
    #pragma unroll
    for (int t = 0; t < 8; ++t) midf[t * 128 + j] = acc[t];
  }
}

__global__ __launch_bounds__(256) void te_fin_kernel(
    const float* __restrict__ midf, const float* __restrict__ l2,
    const float* __restrict__ te, float* __restrict__ tef) {
  __shared__ float mid_s[8 * 128];
  const int tid = threadIdx.x;
  ((f32x4*)mid_s)[tid] = ((const f32x4*)midf)[tid];
  __syncthreads();
  const int d = blockIdx.x * 32 + (tid >> 3);
  const int jseg = (tid & 7) * 16;
  const float* l2r = l2 + (size_t)d * 128 + jseg;
  float wv[16];
  #pragma unroll
  for (int q = 0; q < 4; ++q) {
    const float4 f = ld4(l2r + q * 4);
    wv[q*4] = f.x; wv[q*4+1] = f.y; wv[q*4+2] = f.z; wv[q*4+3] = f.w;
  }
  float acc[8];
  #pragma unroll
  for (int t = 0; t < 8; ++t) {
    float a = 0.f;
    #pragma unroll
    for (int i = 0; i < 16; ++i) a += mid_s[t * 128 + jseg + i] * wv[i];
    acc[t] = a;
  }
  #pragma unroll
  for (int off = 1; off < 8; off <<= 1)
    #pragma unroll
    for (int t = 0; t < 8; ++t) acc[t] += __shfl_xor(acc[t], off);
  if ((tid & 7) == 0) {
    #pragma unroll
    for (int t = 0; t < 8; ++t)
      tef[(size_t)t * DD + d] = te[(size_t)t * DD + d] + acc[t];
  }
}

__global__ __launch_bounds__(256) void te_kv2_kernel(
    const float* __restrict__ tef, const float* __restrict__ W, const float* __restrict__ bias,
    float* __restrict__ tek, float* __restrict__ tev) {
  __shared__ float tes[8 * 1024];
  const int tid = threadIdx.x;
  #pragma unroll
  for (int i = 0; i < 8; ++i)
    ((f32x4*)tes)[tid + i * 256] = ((const f32x4*)tef)[tid + i * 256];
  __syncthreads();
  const int o = blockIdx.x * 32 + (tid >> 3);
  const int ks0 = (tid & 7) * 128;
  const float* wr = W + (size_t)(1024 + o) * DD + ks0;
  float acc[8] = {};
  for (int kk = 0; kk < 128; kk += 4) {
    const float4 w4 = ld4(wr + kk);
    #pragma unroll
    for (int t = 0; t < 8; ++t) {
      const float4 h4 = ld4(tes + t * 1024 + ks0 + kk);
      acc[t] += w4.x*h4.x + w4.y*h4.y + w4.z*h4.z + w4.w*h4.w;
    }
  }
  #pragma unroll
  for (int off = 1; off < 8; off <<= 1)
    #pragma unroll
    for (int t = 0; t < 8; ++t) acc[t] += __shfl_xor(acc[t], off);
  if ((tid & 7) == 0) {
    const float bv = bias[1024 + o];
    float* dst = (o < 1024) ? tek : tev;
    const int oc = o & 1023;
    #pragma unroll
    for (int t = 0; t < 8; ++t) dst[(size_t)t * DD + oc] = acc[t] + bv;
  }
}

// --------------------------------- bf16 MFMA GEMM (proven 2-phase) ----
// Instantiated ONLY at proven shapes: <EPI,64,128> and <2,128,128>.
// QUARANTINE (bisect-convicted): BN=64 tiles (R9/R10), 2-deep counted-vmcnt
// pipeline (R6/R7), attn register prefetch (R13), VGPR-clamp occupancy
// (R11 spills), wide-stage attn (R15 spills).
template<int EPI, int BM, int BN>
__global__ __launch_bounds__(256, 2) void gemm_bf(
    const unsigned short* __restrict__ A, const unsigned short* __restrict__ W,
    const float* __restrict__ bias, const float* __restrict__ res,
    void* __restrict__ Cv, int M, int N, int K, int ny) {
  constexpr int FR = BM / 32;
  constexpr int NB = BN / 32;
  __shared__ unsigned short As[2][BM * 64];
  __shared__ unsigned short Bs[2][BN * 64];
  const int tid = threadIdx.x, w = tid >> 6, l = tid & 63;
  const int lc = l & 15, lg = l >> 4;
  const int nb = gridDim.x;
  const int cid = (blockIdx.x & 7) * (nb >> 3) + (blockIdx.x >> 3);  // XCD chunk
  const int bxt = cid / ny, byt = cid - bxt * ny;
  const int m0 = byt * BM, n0 = bxt * BN;
  const int wm = (w >> 1) * (BM / 2), wn = (w & 1) * (BN / 2);
  const int rrow = tid >> 3;             // 0..31
  const int sblk = (tid & 7) ^ (rrow & 7);   // pre-swizzled source block

  f32x4 acc[FR][NB] = {};

  auto stagef = [&](int kt, int b) {
    const int k0 = kt * 64 + sblk * 8;
    #pragma unroll
    for (int r = 0; r < FR; ++r)
      gld16(A + (size_t)(m0 + r * 32 + rrow) * K + k0, &As[b][r * 2048 + w * 512]);
    #pragma unroll
    for (int r = 0; r < NB; ++r)
      gld16(W + (size_t)(n0 + r * 32 + rrow) * K + k0, &Bs[b][r * 2048 + w * 512]);
  };
  auto computef = [&](int b) {
    const int kx = lc & 7;
    #pragma unroll
    for (int ks = 0; ks < 2; ++ks) {
      u32x4 af[FR], bfr[NB];
      #pragma unroll
      for (int i = 0; i < FR; ++i)
        af[i] = *(const u32x4*)&As[b][(wm + i * 16 + lc) * 64 + ((ks * 4 + lg) ^ kx) * 8];
      #pragma unroll
      for (int j = 0; j < NB; ++j)
        bfr[j] = *(const u32x4*)&Bs[b][(wn + j * 16 + lc) * 64 + ((ks * 4 + lg) ^ kx) * 8];
      #pragma unroll
      for (int i = 0; i < FR; ++i)
        #pragma unroll
        for (int j = 0; j < NB; ++j)
          mfma16(acc[i][j], af[i], bfr[j]);
    }
  };

  const int NT = K >> 6;
  stagef(0, 0);
  asm volatile("s_waitcnt vmcnt(0)" ::: "memory");
  __builtin_amdgcn_s_barrier();
  int cur = 0;
  for (int kt = 0; kt < NT - 1; ++kt) {
    stagef(kt + 1, cur ^ 1);
    computef(cur);
    asm volatile("s_waitcnt vmcnt(0)" ::: "memory");
    __builtin_amdgcn_s_barrier();
    cur ^= 1;
  }
  computef(cur);

  float bias4[NB];
  if (EPI == 1 || EPI == 2 || EPI == 3) {
    #pragma unroll
    for (int j = 0; j < NB; ++j) bias4[j] = bias[n0 + wn + j * 16 + lc];
  }
  #pragma unroll
  for (int i = 0; i < FR; ++i) {
    #pragma unroll
    for (int j = 0; j < NB; ++j) {
      const int col = n0 + wn + j * 16 + lc;
      #pragma unroll
      for (int r = 0; r < 4; ++r) {
        const int row = m0 + wm + i * 16 + lg * 4 + r;
        float x = acc[i][j][r];
        if (EPI == 0) {
          ((unsigned short*)Cv)[(size_t)row * N + col] = (unsigned short)f2bf(x);
        } else if (EPI == 1) {
          x = (x + bias4[j]) * 0.125f;
          ((unsigned short*)Cv)[(size_t)row * N + col] = (unsigned short)f2bf(x);
        } else if (EPI == 2) {
          x += bias4[j];
          x = x / (1.f + __expf(-1.702f * x));
          ((unsigned short*)Cv)[(size_t)row * N + col] = (unsigned short)f2bf(x);
        } else if (EPI == 3) {
          x += bias4[j] + res[(size_t)row * N + col];
          ((float*)Cv)[(size_t)row * N + col] = x;
        } else {
          x += res[(size_t)row * N + col];
          ((float*)Cv)[(size_t)row * N + col] = x;
        }
      }
    }
  }
}

// -------------------------------------------------- MFMA attention ----
// Round-12/14-proven: 4 x {sync, stage 64 keys, sync, compute}, Pl-68
// layout, launch_bounds(256,2).
__global__ __launch_bounds__(256, 2) void attn_mfma(
    const float* __restrict__ ak, const float* __restrict__ av,
    const unsigned short* __restrict__ qbf,
    const float* __restrict__ tek, const float* __restrict__ tev,
    const float* __restrict__ mask, unsigned short* __restrict__ smix) {
  const int h = blockIdx.x, t = blockIdx.y, n = blockIdx.z;
  const int tid = threadIdx.x, w = tid >> 6, l = tid & 63;
  const int lc = l & 15, lg = l >> 4;
  constexpr int HC = HH * CC;
  __shared__ unsigned short Ks[64][72];
  __shared__ unsigned short Vt[64][72];
  __shared__ unsigned short Pl[4][64][68];

  u32x4 qf[4][2];
  {
    const unsigned short* qb = qbf + ((size_t)(n * QQ + w * 64 + lc)) * DD + h * CC + lg * 8;
    #pragma unroll
    for (int fnq = 0; fnq < 4; ++fnq)
      #pragma unroll
      for (int ks = 0; ks < 2; ++ks)
        qf[fnq][ks] = *(const u32x4*)(qb + (size_t)fnq * 16 * DD + ks * 32);
  }
  // qte[fnq] = (q*scale) . te_k
  float qte4[4];
  {
    float tkc[16];
    const float* tp = tek + (size_t)t * DD + h * CC + lg * 8;
    #pragma unroll
    for (int ks = 0; ks < 2; ++ks) {
      const float4 a = ld4(tp + ks * 32);
      const float4 b = ld4(tp + ks * 32 + 4);
      tkc[ks*8]   = a.x; tkc[ks*8+1] = a.y; tkc[ks*8+2] = a.z; tkc[ks*8+3] = a.w;
      tkc[ks*8+4] = b.x; tkc[ks*8+5] = b.y; tkc[ks*8+6] = b.z; tkc[ks*8+7] = b.w;
    }
    #pragma unroll
    for (int fnq = 0; fnq < 4; ++fnq) {
      float p = 0.f;
      #pragma unroll
      for (int ks = 0; ks < 2; ++ks)
        #pragma unroll
        for (int e = 0; e < 4; ++e) {
          const unsigned int u = qf[fnq][ks][e];
          p += bf2f(u & 0xffffu) * tkc[ks*8 + e*2];
          p += bf2f(u >> 16)     * tkc[ks*8 + e*2 + 1];
        }
      p += __shfl_xor(p, 16);
      p += __shfl_xor(p, 32);
      qte4[fnq] = p;
    }
  }

  f32x4 oacc[4][4] = {};
  float mrun[4], lrun[4];
  #pragma unroll
  for (int i = 0; i < 4; ++i) { mrun[i] = -1e30f; lrun[i] = 0.f; }

  const size_t krow0 = (((size_t)(n * TT + t) * LL + 1) * HH + h) * CC;
  const float* mbase = mask + (size_t)(w * 64) * QQ;

  for (int c0 = 0; c0 < QQ; c0 += 64) {
    __syncthreads();
    {   // stage K row-major [key][c]
      const int kr = tid >> 2, cs = (tid & 3) * 16;
      const float* kp = ak + krow0 + (size_t)(c0 + kr) * HC + cs;
      const float4 k0 = ld4(kp), k1 = ld4(kp + 4), k2 = ld4(kp + 8), k3 = ld4(kp + 12);
      u32x4 pa; pa.x = cvtpk(k0.x, k0.y); pa.y = cvtpk(k0.z, k0.w);
      pa.z = cvtpk(k1.x, k1.y); pa.w = cvtpk(k1.z, k1.w);
      u32x4 pb; pb.x = cvtpk(k2.x, k2.y); pb.y = cvtpk(k2.z, k2.w);
      pb.z = cvtpk(k3.x, k3.y); pb.w = cvtpk(k3.z, k3.w);
      *(u32x4*)&Ks[kr][cs] = pa;
      *(u32x4*)&Ks[kr][cs + 8] = pb;
    }
    {   // stage V transposed [c][key]
      const int kp2 = tid & 31, ch = tid >> 5;
      const float* vr0 = av + krow0 + (size_t)(c0 + 2 * kp2) * HC + ch * 8;
      const float* vr1 = vr0 + HC;
      const float4 a0 = ld4(vr0), a1 = ld4(vr0 + 4);
      const float4 b0 = ld4(vr1), b1 = ld4(vr1 + 4);
      const float va[8] = {a0.x,a0.y,a0.z,a0.w,a1.x,a1.y,a1.z,a1.w};
      const float vb[8] = {b0.x,b0.y,b0.z,b0.w,b1.x,b1.y,b1.z,b1.w};
      #pragma unroll
      for (int i = 0; i < 8; ++i)
        *(unsigned int*)&Vt[ch * 8 + i][2 * kp2] = cvtpk(va[i], vb[i]);
    }
    __syncthreads();

    f32x4 sf[4][4] = {};
    __builtin_amdgcn_s_setprio(1);
    #pragma unroll
    for (int ks = 0; ks < 2; ++ks) {
      u32x4 kf[4];
      #pragma unroll
      for (int fmk = 0; fmk < 4; ++fmk)
        kf[fmk] = *(const u32x4*)&Ks[fmk * 16 + lc][ks * 32 + lg * 8];
      #pragma unroll
      for (int fmk = 0; fmk < 4; ++fmk)
        #pragma unroll
        for (int fnq = 0; fnq < 4; ++fnq)
          mfma16(sf[fmk][fnq], kf[fmk], qf[fnq][ks]);
    }
    __builtin_amdgcn_s_setprio(0);

    #pragma unroll
    for (int fnq = 0; fnq < 4; ++fnq) {
      const float* mrow = mbase + (size_t)(fnq * 16 + lc) * QQ + c0 + lg * 4;
      const float qv = qte4[fnq];
      #pragma unroll
      for (int fmk = 0; fmk < 4; ++fmk) {
        const f32x4 mk = *(const f32x4*)(mrow + fmk * 16);
        sf[fmk][fnq] += mk + qv;
      }
      float mx = -1e30f;
      #pragma unroll
      for (int fmk = 0; fmk < 4; ++fmk) {
        mx = fmaxf(mx, fmaxf(fmaxf(sf[fmk][fnq][0], sf[fmk][fnq][1]),
                             fmaxf(sf[fmk][fnq][2], sf[fmk][fnq][3])));
      }
      mx = fmaxf(mx, __shfl_xor(mx, 16));
      mx = fmaxf(mx, __shfl_xor(mx, 32));
      const float mnew = fmaxf(mrun[fnq], mx);
      const float corr = __expf(mrun[fnq] - mnew);
      mrun[fnq] = mnew;
      float ls = 0.f;
      #pragma unroll
      for (int fmk = 0; fmk < 4; ++fmk) {
        const float p0 = __expf(sf[fmk][fnq][0] - mnew);
        const float p1 = __expf(sf[fmk][fnq][1] - mnew);
        const float p2 = __expf(sf[fmk][fnq][2] - mnew);
        const float p3 = __expf(sf[fmk][fnq][3] - mnew);
        ls += (p0 + p1) + (p2 + p3);
        u32x2 pw; pw.x = cvtpk(p0, p1); pw.y = cvtpk(p2, p3);
        *(u32x2*)&Pl[w][fnq * 16 + lc][fmk * 16 + lg * 4] = pw;
      }
      ls += __shfl_xor(ls, 16);
      ls += __shfl_xor(ls, 32);
      lrun[fnq] = lrun[fnq] * corr + ls;
      #pragma unroll
      for (int fmc = 0; fmc < 4; ++fmc) oacc[fmc][fnq] *= corr;
    }

    __builtin_amdgcn_s_setprio(1);
    #pragma unroll
    for (int ks = 0; ks < 2; ++ks) {
      u32x4 vf[4], pf[4];
      #pragma unroll
      for (int fmc = 0; fmc < 4; ++fmc)
        vf[fmc] = *(const u32x4*)&Vt[fmc * 16 + lc][ks * 32 + lg * 8];
      #pragma unroll
      for (int fnq = 0; fnq < 4; ++fnq) {
        const u32x2 pa = *(const u32x2*)&Pl[w][fnq * 16 + lc][ks * 32 + lg * 8];
        const u32x2 pb = *(const u32x2*)&Pl[w][fnq * 16 + lc][ks * 32 + lg * 8 + 4];
        pf[fnq].x = pa.x; pf[fnq].y = pa.y; pf[fnq].z = pb.x; pf[fnq].w = pb.y;
      }
      #pragma unroll
      for (int fmc = 0; fmc < 4; ++fmc)
        #pragma unroll
        for (int fnq = 0; fnq < 4; ++fnq)
          mfma16(oacc[fmc][fnq], vf[fmc], pf[fnq]);
    }
    __builtin_amdgcn_s_setprio(0);
  }

  // epilogue: O/l + te_v  -> smix bf16
  f32x4 tev4[4];
  {
    const float* tvp = tev + (size_t)t * DD + h * CC + lg * 4;
    #pragma unroll
    for (int fmc = 0; fmc < 4; ++fmc) tev4[fmc] = *(const f32x4*)(tvp + fmc * 16);
  }
  #pragma unroll
  for (int fnq = 0; fnq < 4; ++fnq) {
    const float inv = 1.f / lrun[fnq];
    const int qg = w * 64 + fnq * 16 + lc;
    unsigned short* op = smix + ((((size_t)(n * TT + t) * QQ + qg) * HH + h) * CC + lg * 4);
    #pragma unroll
    for (int fmc = 0; fmc < 4; ++fmc) {
      const f32x4 o = oacc[fmc][fnq] * inv + tev4[fmc];
      u32x2 p; p.x = cvtpk(o[0], o[1]); p.y = cvtpk(o[2], o[3]);
      *(u32x2*)(op + fmc * 16) = p;
    }
  }
}

// -------------------------------------------- conv3+mean_t combine ----
__global__ __launch_bounds__(256) void combine_kernel(
    const unsigned short* __restrict__ smix, const float* __restrict__ cw,
    const float* __restrict__ cb, unsigned short* __restrict__ smm) {
  const int nq = blockIdx.x;
  const int d = threadIdx.x * 4;
  const int n = nq >> 8, q = nq & 255;
  const unsigned short* base = smix + ((size_t)n * TT * QQ + q) * DD + d;
  float S[4] = {0.f, 0.f, 0.f, 0.f};
  float X0[4], X7[4];
  #pragma unroll
  for (int t = 0; t < TT; ++t) {
    const u32x2 pv = *(const u32x2*)(base + (size_t)t * QQ * DD);
    const float v[4] = {bf2f(pv.x & 0xffffu), bf2f(pv.x >> 16),
                        bf2f(pv.y & 0xffffu), bf2f(pv.y >> 16)};
    if (t == 0) { X0[0]=v[0]; X0[1]=v[1]; X0[2]=v[2]; X0[3]=v[3]; }
    if (t == 7) { X7[0]=v[0]; X7[1]=v[1]; X7[2]=v[2]; X7[3]=v[3]; }
    #pragma unroll
    for (int i = 0; i < 4; ++i) S[i] += v[i];
  }
  float o[4];
  #pragma unroll
  for (int i = 0; i < 4; ++i) {
    const int chn = d + i;
    const float w0 = cw[chn*3+0], w1 = cw[chn*3+1], w2 = cw[chn*3+2];
    o[i] = ((1.f + w0 + w1 + w2) * S[i] - w0 * X7[i] - w2 * X0[i]) * 0.125f + cb[chn];
  }
  u32x2 p; p.x = pk2(o[0], o[1]); p.y = pk2(o[2], o[3]);
  *(u32x2*)(smm + (size_t)nq * DD + d) = p;
}

// ------------------------------------------------------------ launch ----
extern "C" void kernel_launch(void* const* d_in, const int* in_sizes, int n_in,
                              void* d_out, int out_size, void* d_ws, size_t ws_size,
                              hipStream_t stream) {
  const float* attrs_k = (const float*)d_in[0];
  const float* attrs_v = (const float*)d_in[1];
  const float* s       = (const float*)d_in[2];
  const float* te      = (const float*)d_in[3];
  const float* pmask   = (const float*)d_in[4];
  const float* ln1_w   = (const float*)d_in[5];
  const float* ln1_b   = (const float*)d_in[6];
  const float* inW     = (const float*)d_in[7];
  const float* inB     = (const float*)d_in[8];
  const float* outW    = (const float*)d_in[9];
  const float* outB    = (const float*)d_in[10];
  const float* ln2_w   = (const float*)d_in[11];
  const float* ln2_b   = (const float*)d_in[12];
  const float* fcW     = (const float*)d_in[13];
  const float* fcB     = (const float*)d_in[14];
  const float* pjW     = (const float*)d_in[15];
  const float* pjB     = (const float*)d_in[16];
  const float* sylnW   = (const float*)d_in[17];
  const float* sylnB   = (const float*)d_in[18];
  const float* syl1    = (const float*)d_in[19];
  const float* syl2    = (const float*)d_in[20];
  const float* telnW   = (const float*)d_in[21];
  const float* telnB   = (const float*)d_in[22];
  const float* tel1    = (const float*)d_in[23];
  const float* tel2    = (const float*)d_in[24];
  const float* tconvW  = (const float*)d_in[25];
  const float* tconvB  = (const float*)d_in[26];

  float* ws = (float*)d_ws;
  float*          f_te   = ws;                                  // 8192 (= _te)
  float*          f_tek  = ws + 8192;                           // 8192
  float*          f_tev  = ws + 16384;                          // 8192
  unsigned short* telnb  = (unsigned short*)(ws + 24576);       // 4096 f
  float*          midf   = ws + 28672;                          // 1024 f
  unsigned short* syl1b  = (unsigned short*)(ws + 32768);       // 65536 f
  unsigned short* syl2b  = (unsigned short*)(ws + 98304);       // 65536 f
  unsigned short* midb   = (unsigned short*)(ws + 163840);      // 131072 f
  unsigned short* bufAb  = (unsigned short*)(ws + 327680);      // 524288 f (LN outs)
  unsigned short* qbf    = (unsigned short*)(ws + 851968);      // 524288 f
  unsigned short* smmb   = (unsigned short*)(ws + 1376256);     // 524288 f
  unsigned short* wqb    = (unsigned short*)(ws + 1900544);     // 524288 f
  unsigned short* outwb  = (unsigned short*)(ws + 2424832);     // 524288 f
  unsigned short* fcwb   = (unsigned short*)(ws + 2949120);     // 2097152 f
  unsigned short* pjwb   = (unsigned short*)(ws + 5046272);     // 2097152 f
  float*          bufB   = ws + 7143424;                        // 2097152 f (_s)
  unsigned short* smixb  = (unsigned short*)(ws + 9240576);     // 8388608 f region
  float*          s1     = ws + 9240576;                        // overlay (smix dead)
  unsigned short* hmidb  = (unsigned short*)(ws + 9240576 + 2097152); // 4194304 f
  float*          outp   = (float*)d_out;

  // 0. fused weight conversions f32 -> bf16
  cvt_all_kernel<<<10496, 256, 0, stream>>>(inW, outW, fcW, pjW, syl1, syl2,
                                            wqb, outwb, fcwb, pjwb, syl1b, syl2b);

  // 1. te adaptor pipeline + te k/v
  ln_bf_kernel<<<TT, 256, 0, stream>>>(te, telnW, telnB, telnb);
  te_mid_kernel<<<32, 256, 0, stream>>>(telnb, tel1, midf);
  te_fin_kernel<<<32, 256, 0, stream>>>(midf, tel2, te, f_te);
  te_kv2_kernel<<<64, 256, 0, stream>>>(f_te, inW, inB, f_tek, f_tev);

  // 2. syno adaptor: h = LN(s) [bf16]
  ln_bf_kernel<<<NQ, 256, 0, stream>>>(s, sylnW, sylnB, bufAb);
  // 3. mid = h @ l1^T  [bf16]
  gemm_bf<0, 64, 128><<<32, 256, 0, stream>>>(bufAb, syl1b, nullptr, nullptr, midb, NQ, 128, DD, 32);
  // 4. _s = s + mid @ l2^T  [f32]
  gemm_bf<4, 64, 128><<<256, 256, 0, stream>>>(midb, syl2b, nullptr, s, bufB, NQ, DD, 128, 32);
  // 5. x = LN1(_s) [bf16]
  ln_bf_kernel<<<NQ, 256, 0, stream>>>(bufB, ln1_w, ln1_b, bufAb);
  // 6. s_q = (x @ Wq^T + bq) * 0.125 [bf16]
  gemm_bf<1, 64, 128><<<256, 256, 0, stream>>>(bufAb, wqb, inB, nullptr, qbf, NQ, DD, DD, 32);
  // 7. attention -> smix bf16 (includes te_v)
  attn_mfma<<<dim3(HH, TT, NN), 256, 0, stream>>>(attrs_k, attrs_v, qbf, f_tek, f_tev, pmask, smixb);
  // 8. conv+mean combine -> smm bf16
  combine_kernel<<<NQ, 256, 0, stream>>>(smixb, tconvW, tconvB, smmb);
  // 9. s1 = s + smm @ outW^T + outB [f32]
  gemm_bf<3, 64, 128><<<256, 256, 0, stream>>>(smmb, outwb, outB, s, s1, NQ, DD, DD, 32);
  // 10. x2 = LN2(s1) [bf16]
  ln_bf_kernel<<<NQ, 256, 0, stream>>>(s1, ln2_w, ln2_b, bufAb);
  // 11. hmid = qgelu(x2 @ fcW^T + fcB) [bf16] (128x128 tile)
  gemm_bf<2, 128, 128><<<512, 256, 0, stream>>>(bufAb, fcwb, fcB, nullptr, hmidb, NQ, 4 * DD, DD, 16);
  // 12. out = s1 + hmid @ pjW^T + pjB [f32]
  gemm_bf<3, 64, 128><<<256, 256, 0, stream>>>(hmidb, pjwb, pjB, s1, outp, NQ, DD, 4 * DD, 32);
}